// Round 11
// baseline (90.880 us; speedup 1.0000x reference)
//
#include <hip/hip_runtime.h>
#include <hip/hip_bf16.h>
#include <math.h>

// B=2, C=128, T=5 (Tc=4 ctx), H=W=48, heads=64, PATCH=7 (pad 3), K=196.
#define BATCH 2
#define CCH 128
#define TT 5
#define TC 4
#define HH 48
#define WW 48
#define HWPIX 2304
#define NHEAD 64
#define PAD 3
#define XSTRIDE (TT*HWPIX)      // per-channel stride in x
#define PLANE (HWPIX*NHEAD)     // elements per UNPADDED (b,t) phi/g plane
#define GOFF (BATCH*TC*PLANE)   // g planes offset from phi planes (elements)

// fused-attn tile geometry: 2x2 pixel tile (R11: occupancy experiment)
#define TW 2
#define TH 2
#define WROWS 8                 // TH + 6
#define WCOLS 8                 // TW + 6
#define NRC 64                  // WROWS*WCOLS
#define WELEM (NRC*NHEAD)       // 4096 bf16 per window buffer
#define SMEMB 35904             // max(win 32768, wo_s 34816 + y_s 1088)

#define WPITCH 136              // proj LDS pitch (bf16): 272B rows -> 2-way bank alias (free)

typedef unsigned short bf16_t;

static __device__ __forceinline__ bf16_t f2bf(float f) {
    unsigned u = __float_as_uint(f);
    u += 0x7FFFu + ((u >> 16) & 1u);          // round-to-nearest-even
    return (bf16_t)(u >> 16);
}
static __device__ __forceinline__ float bf_lo(unsigned u) {
    return __uint_as_float(u << 16);
}
static __device__ __forceinline__ float bf_hi(unsigned u) {
    return __uint_as_float(u & 0xFFFF0000u);
}
static __device__ __forceinline__ int iclamp(int v, int lo, int hi) {
    return v < lo ? lo : (v > hi ? hi : v);
}

// v_dot2_f32_bf16 path (hedged: falls back to unpack+fma if unavailable)
#if defined(__has_builtin)
#if __has_builtin(__builtin_amdgcn_fdot2_f32_bf16) && __has_builtin(__builtin_amdgcn_perm)
#define HAVE_DOT2 1
#endif
#endif

#ifdef HAVE_DOT2
typedef __bf16 bf16x2_t __attribute__((ext_vector_type(2)));
static __device__ __forceinline__ float dot2bf(unsigned g2, unsigned a2, float c) {
    return __builtin_amdgcn_fdot2_f32_bf16(
        __builtin_bit_cast(bf16x2_t, g2), __builtin_bit_cast(bf16x2_t, a2), c, false);
}
static __device__ __forceinline__ unsigned perm_lo(unsigned a, unsigned b) {
    return __builtin_amdgcn_perm(a, b, 0x05040100u);
}
static __device__ __forceinline__ unsigned perm_hi(unsigned a, unsigned b) {
    return __builtin_amdgcn_perm(a, b, 0x07060302u);
}
#else
static __device__ __forceinline__ float dot2bf(unsigned g2, unsigned a2, float c) {
    return c + bf_lo(g2) * bf_lo(a2) + bf_hi(g2) * bf_hi(a2);
}
#endif

typedef __attribute__((ext_vector_type(8))) short bf16x8;
typedef __attribute__((ext_vector_type(4))) float f32x4;

// ---------------------------------------------------------------------------
// K1: projections — MFMA, 64-px blocks (R9, unchanged).
// ---------------------------------------------------------------------------
__global__ __launch_bounds__(256) void proj_kernel(
    const float* __restrict__ x,
    const float* __restrict__ w_theta,
    const float* __restrict__ w_phi,
    const float* __restrict__ w_g,
    bf16_t* __restrict__ q_b,
    bf16_t* __restrict__ phi_b,
    bf16_t* __restrict__ g_b)
{
    __shared__ bf16_t xs[64 * WPITCH];      // 17.4 KB [px][c]
    __shared__ bf16_t wla[64 * WPITCH];     // 17.4 KB [h][c]  theta/phi
    __shared__ bf16_t wlb[64 * WPITCH];     // 17.4 KB [h][c]  g

    const int bt   = blockIdx.y;        // 0..9
    const int b    = bt / TT;
    const int t    = bt % TT;
    const int tid  = threadIdx.x;
    const int lane = tid & 63;
    const int wv   = tid >> 6;          // 0..3 = 16-px tile
    const int p0   = blockIdx.x * 64;

    // ---- stage weights from fp32, packing to bf16 [h][c] rows ----
    {
        const float* srcA = (t == 0) ? w_theta : w_phi;
#pragma unroll
        for (int i = 0; i < 4; ++i) {
            const int idx = i * 256 + tid;   // 0..1023
            const int h   = idx >> 4;        // 0..63
            const int ck  = idx & 15;        // chunk 0..15
            const float* s = srcA + h * CCH + ck * 8;
            const float4 v0 = *(const float4*)(s);
            const float4 v1 = *(const float4*)(s + 4);
            uint4 o;
            o.x = (unsigned)f2bf(v0.x) | ((unsigned)f2bf(v0.y) << 16);
            o.y = (unsigned)f2bf(v0.z) | ((unsigned)f2bf(v0.w) << 16);
            o.z = (unsigned)f2bf(v1.x) | ((unsigned)f2bf(v1.y) << 16);
            o.w = (unsigned)f2bf(v1.z) | ((unsigned)f2bf(v1.w) << 16);
            *(uint4*)&wla[h * WPITCH + ck * 8] = o;
        }
        if (t != 0) {
#pragma unroll
            for (int i = 0; i < 4; ++i) {
                const int idx = i * 256 + tid;
                const int h   = idx >> 4;
                const int ck  = idx & 15;
                const float* s = w_g + h * CCH + ck * 8;
                const float4 v0 = *(const float4*)(s);
                const float4 v1 = *(const float4*)(s + 4);
                uint4 o;
                o.x = (unsigned)f2bf(v0.x) | ((unsigned)f2bf(v0.y) << 16);
                o.y = (unsigned)f2bf(v0.z) | ((unsigned)f2bf(v0.w) << 16);
                o.z = (unsigned)f2bf(v1.x) | ((unsigned)f2bf(v1.y) << 16);
                o.w = (unsigned)f2bf(v1.z) | ((unsigned)f2bf(v1.w) << 16);
                *(uint4*)&wlb[h * WPITCH + ck * 8] = o;
            }
        }
    }

    // ---- stage x tile as bf16 [px][c] (lanes over 64 px: 256B coalesced) ----
    {
        const float* xsrc = x + ((size_t)(b * CCH) * TT + t) * HWPIX + p0;
#pragma unroll
        for (int i = 0; i < 16; ++i) {
            const int idx = i * 256 + tid;  // 0..4095
            const int cp  = idx >> 6;       // c-pair 0..63
            const int px  = idx & 63;
            const float a0 = xsrc[(size_t)(2 * cp)     * XSTRIDE + px];
            const float a1 = xsrc[(size_t)(2 * cp + 1) * XSTRIDE + px];
            *(unsigned*)&xs[px * WPITCH + 2 * cp] =
                (unsigned)f2bf(a0) | ((unsigned)f2bf(a1) << 16);
        }
    }
    __syncthreads();

    // ---- MFMA K-loop ----
    const int arow = wv * 16 + (lane & 15);
    const int koff = (lane >> 4) * 8;

    bf16x8 afr[4];
#pragma unroll
    for (int kk = 0; kk < 4; ++kk)
        afr[kk] = *(const bf16x8*)&xs[arow * WPITCH + koff + 32 * kk];

    const int hrow16 = lane & 15;              // B-frag row within h-tile
    const int prow_  = (lane >> 4) * 4;        // D row base (px within tile)
    const int hcol   = lane & 15;              // D col (h within 16-tile)

    if (t == 0) {
#pragma unroll
        for (int ht = 0; ht < 4; ++ht) {
            f32x4 acc = {0.f, 0.f, 0.f, 0.f};
#pragma unroll
            for (int kk = 0; kk < 4; ++kk) {
                const bf16x8 bfr = *(const bf16x8*)&wla[(ht * 16 + hrow16) * WPITCH + koff + 32 * kk];
                acc = __builtin_amdgcn_mfma_f32_16x16x32_bf16(afr[kk], bfr, acc, 0, 0, 0);
            }
            const int h = ht * 16 + hcol;
#pragma unroll
            for (int r = 0; r < 4; ++r) {
                const int px = p0 + wv * 16 + prow_ + r;
                q_b[((size_t)b * HWPIX + px) * NHEAD + h] = f2bf(acc[r]);
            }
        }
    } else {
        const size_t base = (size_t)(b * TC + (t - 1)) * PLANE;
#pragma unroll
        for (int pr = 0; pr < 2; ++pr) {
            const bf16_t* wl = pr ? wlb : wla;
            bf16_t* dst = pr ? g_b : phi_b;
#pragma unroll
            for (int ht = 0; ht < 4; ++ht) {
                f32x4 acc = {0.f, 0.f, 0.f, 0.f};
#pragma unroll
                for (int kk = 0; kk < 4; ++kk) {
                    const bf16x8 bfr = *(const bf16x8*)&wl[(ht * 16 + hrow16) * WPITCH + koff + 32 * kk];
                    acc = __builtin_amdgcn_mfma_f32_16x16x32_bf16(afr[kk], bfr, acc, 0, 0, 0);
                }
                const int h = ht * 16 + hcol;
#pragma unroll
                for (int r = 0; r < 4; ++r) {
                    const int px = p0 + wv * 16 + prow_ + r;
                    dst[base + (size_t)px * NHEAD + h] = f2bf(acc[r]);
                }
            }
        }
    }
}

// ---------------------------------------------------------------------------
// K2: FUSED attention + combine + out-proj + residual — 2x2-tile version.
// R11 (occupancy experiment): 1152 blocks x 256 thr (4 blocks/CU resident =
// 16 waves/CU, was 9). Wave = one pixel, 64 lanes: logits 1 key/lane
// (k = 2*sub + half, 32 dot2 — halved), PV par 8-wide (64 dot2 — halved),
// 6-step max reduce, ls2 packed via one lane^32 shfl. Barrier group stays
// 4 waves (R5's 8-wave groups were the confound). Staging = 4 uint4/thread
// exactly. XCD-chunked swizzle (1152 = 8*144).
// ---------------------------------------------------------------------------
__global__ __launch_bounds__(256) void attn_fused_kernel(
    const float* __restrict__ x,
    const bf16_t* __restrict__ q_b,
    const bf16_t* __restrict__ pg,      // phi planes; g planes at pg + GOFF
    const float* __restrict__ w_out,
    float* __restrict__ out)
{
    __shared__ __align__(16) char smem[SMEMB];
    __shared__ unsigned ls2[4][26];
    __shared__ unsigned prow[26];

    const int tid  = threadIdx.x;
    const int px   = tid >> 6;          // 0..3 pixel of tile (= wave id)
    const int lane = tid & 63;
    const int sub  = lane & 31;
    const int g    = lane >> 5;         // key parity half

    // ---- XCD-chunked swizzle: 1152 = 8 * 144 ----
    const int bid = blockIdx.x;
    const int lin = (bid & 7) * 144 + (bid >> 3);
    const int b   = lin / 576;
    const int rem = lin - b * 576;
    const int ty  = rem / 24;
    const int tx  = rem - ty * 24;
    const int Y0  = tx * TW;
    const int X0  = ty * TH;

    const int rr  = px >> 1;
    const int cc  = px & 1;
    const int gpix  = (X0 + rr) * WW + Y0 + cc;
    const int pxoff = rr * WCOLS + cc;
    const int oct = lane >> 3;          // 0..7 head octet
    const int par = lane & 7;           // 0..7 key-pair subset

    // ---- q fragments (64 h = 8 uint4), broadcast across the wave ----
    uint4 qu[8];
    {
        const uint4* qs = (const uint4*)(q_b + ((size_t)b * HWPIX + gpix) * NHEAD);
#pragma unroll
        for (int ch = 0; ch < 8; ++ch) qu[ch] = qs[ch];
    }

    if (tid < 25) {
        const int k0 = 2 * tid;
        const int k1 = (k0 + 1 < 49) ? k0 + 1 : 48;
        const unsigned r0 = (unsigned)((k0 / 7) * WCOLS + (k0 % 7));
        const unsigned r1 = (unsigned)((k1 / 7) * WCOLS + (k1 % 7));
        prow[tid] = r0 | (r1 << 16);
    }

    // ---- staging offsets: 1024 uint4 per stage = 4/thread exactly.
    //      Replicate padding realized here: clamp window coords to [0,47]. ----
    int srcoff[4], lddst[4];
#pragma unroll
    for (int ii = 0; ii < 4; ++ii) {
        const int idx  = ii * 256 + tid;          // 0..1023
        const int isg  = (idx >= 512) ? 1 : 0;    // 0: phi, 1: g
        const int idx2 = idx - (isg ? 512 : 0);
        const int row  = idx2 >> 3;               // 0..63
        const int ch   = idx2 & 7;
        const int i    = row >> 3;                // 0..7
        const int c    = row & 7;
        const int xr   = iclamp(X0 + i - PAD, 0, HH - 1);
        const int yc   = iclamp(Y0 + c - PAD, 0, WW - 1);
        srcoff[ii] = isg * GOFF + (xr * WW + yc) * NHEAD + ch * 8;
        lddst[ii]  = isg * (2 * WELEM) + row * NHEAD + (((ch + row) & 7) << 3);
    }

    bf16_t* winb = (bf16_t*)smem;   // [phi0 | phi1 | g0 | g1], 4096 elems each

    // ---- prologue: stage t=0 into parity 0 ----
    {
        const bf16_t* sp = pg + (size_t)(b * TC) * PLANE;
#pragma unroll
        for (int ii = 0; ii < 4; ++ii) {
            const uint4 v = *(const uint4*)(sp + srcoff[ii]);
            *(uint4*)(winb + lddst[ii]) = v;
        }
    }
    __syncthreads();

    float m_run = -INFINITY, l_part = 0.f;
    float acc[8];
#pragma unroll
    for (int e = 0; e < 8; ++e) acc[e] = 0.f;

    const int k    = 2 * sub + g;                  // this lane's key
    const int kvalid = (sub < 25) && (k < 49);
    const int krow = kvalid ? ((k / 7) * WCOLS + (k % 7) + pxoff) : 0;

    for (int t = 0; t < TC; ++t) {
        const int p = t & 1;

        // ---- issue next-t loads early (hidden under logits+PV) ----
        uint4 stg[4];
        if (t < TC - 1) {
            const bf16_t* sp = pg + (size_t)(b * TC + t + 1) * PLANE;
#pragma unroll
            for (int ii = 0; ii < 4; ++ii)
                stg[ii] = *(const uint4*)(sp + srcoff[ii]);
        }

        __builtin_amdgcn_s_setprio(1);

        // ---- logits: ONE key per lane (k = 2*sub + g), split chains ----
        const bf16_t* pbase = winb + p * WELEM;
        float v = -INFINITY;
        if (kvalid) {
            const bf16_t* base = pbase + krow * NHEAD;
            float sa = 0.f, sb = 0.f;
#pragma unroll
            for (int ch = 0; ch < 4; ++ch) {
                const uint4 u  = *(const uint4*)&base[((ch + krow) & 7) << 3];
                const uint4 u2 = *(const uint4*)&base[((ch + 4 + krow) & 7) << 3];
                sa = dot2bf(u.x,  qu[ch].x,     sa);
                sa = dot2bf(u.y,  qu[ch].y,     sa);
                sa = dot2bf(u.z,  qu[ch].z,     sa);
                sa = dot2bf(u.w,  qu[ch].w,     sa);
                sb = dot2bf(u2.x, qu[ch + 4].x, sb);
                sb = dot2bf(u2.y, qu[ch + 4].y, sb);
                sb = dot2bf(u2.z, qu[ch + 4].z, sb);
                sb = dot2bf(u2.w, qu[ch + 4].w, sb);
            }
            v = (sa + sb) * 8.0f;    // * sqrt(64)
        }

        // ---- online softmax: 6-step wave max; sum deferred ----
        float mt = v;
#pragma unroll
        for (int d = 1; d < 64; d <<= 1) mt = fmaxf(mt, __shfl_xor(mt, d));
        const float m_new = fmaxf(m_run, mt);
        const float sc = __expf(m_run - m_new);
        const float e0 = kvalid ? __expf(v - m_new) : 0.f;
        l_part = l_part * sc + e0;
        m_run = m_new;

        // partner (lane^32) holds the odd key of this lane's pair
        const float e1 = __shfl_xor(e0, 32);
        if (g == 0 && sub < 25)
            ls2[px][sub] = (unsigned)f2bf(e0) | ((unsigned)f2bf(e1) << 16);

        // ---- PV accumulate with rescale: 8 octets x 8 subsets ----
#pragma unroll
        for (int e = 0; e < 8; ++e) acc[e] *= sc;
        const bf16_t* gbase = winb + 2 * WELEM + p * WELEM;
#pragma unroll
        for (int mi = 0; mi < 4; ++mi) {
            const int pm = par + 8 * mi;
            if (pm < 25) {
                const unsigned pr = prow[pm];
                const int row0 = (int)(pr & 0xFFFFu) + pxoff;
                const int row1 = (int)(pr >> 16) + pxoff;
                const uint4 u0 = *(const uint4*)&gbase[row0 * NHEAD + (((oct + row0) & 7) << 3)];
                const uint4 u1 = *(const uint4*)&gbase[row1 * NHEAD + (((oct + row1) & 7) << 3)];
#ifdef HAVE_DOT2
                const unsigned a2 = ls2[px][pm];
                acc[0] = dot2bf(perm_lo(u1.x, u0.x), a2, acc[0]);
                acc[1] = dot2bf(perm_hi(u1.x, u0.x), a2, acc[1]);
                acc[2] = dot2bf(perm_lo(u1.y, u0.y), a2, acc[2]);
                acc[3] = dot2bf(perm_hi(u1.y, u0.y), a2, acc[3]);
                acc[4] = dot2bf(perm_lo(u1.z, u0.z), a2, acc[4]);
                acc[5] = dot2bf(perm_hi(u1.z, u0.z), a2, acc[5]);
                acc[6] = dot2bf(perm_lo(u1.w, u0.w), a2, acc[6]);
                acc[7] = dot2bf(perm_hi(u1.w, u0.w), a2, acc[7]);
#else
                const unsigned a2 = ls2[px][pm];
                const float a0 = bf_lo(a2), a1 = bf_hi(a2);
                acc[0] = fmaf(a1, bf_lo(u1.x), fmaf(a0, bf_lo(u0.x), acc[0]));
                acc[1] = fmaf(a1, bf_hi(u1.x), fmaf(a0, bf_hi(u0.x), acc[1]));
                acc[2] = fmaf(a1, bf_lo(u1.y), fmaf(a0, bf_lo(u0.y), acc[2]));
                acc[3] = fmaf(a1, bf_hi(u1.y), fmaf(a0, bf_hi(u0.y), acc[3]));
                acc[4] = fmaf(a1, bf_lo(u1.z), fmaf(a0, bf_lo(u0.z), acc[4]));
                acc[5] = fmaf(a1, bf_hi(u1.z), fmaf(a0, bf_hi(u0.z), acc[5]));
                acc[6] = fmaf(a1, bf_lo(u1.w), fmaf(a0, bf_lo(u0.w), acc[6]));
                acc[7] = fmaf(a1, bf_hi(u1.w), fmaf(a0, bf_hi(u0.w), acc[7]));
#endif
            }
        }

        __builtin_amdgcn_s_setprio(0);

        // ---- write-late: next-t windows into alternate buffers ----
        if (t < TC - 1) {
            bf16_t* dp = winb + (p ^ 1) * WELEM;   // g offset baked into lddst
#pragma unroll
            for (int ii = 0; ii < 4; ++ii)
                *(uint4*)(dp + lddst[ii]) = stg[ii];
        }
        __syncthreads();
    }

    // ---- deferred l reduce (once), then par reduce of acc ----
#pragma unroll
    for (int d = 1; d < 64; d <<= 1) l_part += __shfl_xor(l_part, d);
#pragma unroll
    for (int e = 0; e < 8; ++e) {
        acc[e] += __shfl_xor(acc[e], 1);
        acc[e] += __shfl_xor(acc[e], 2);
        acc[e] += __shfl_xor(acc[e], 4);
    }
    const float inv = 1.0f / l_part;

    // ---- epilogue: alias win LDS as w_out tile + y tile ----
    float* wo_s = (float*)smem;                        // [128][68] = 34816 B
    float* y_s  = (float*)(smem + 34816);              // [4][68]   =  1088 B

#pragma unroll
    for (int ii = 0; ii < 8; ++ii) {
        const int idx = ii * 256 + tid;    // 0..2047
        const int c   = idx >> 4;
        const int hq  = idx & 15;
        const float4 v = *(const float4*)(w_out + (size_t)c * NHEAD + hq * 4);
        *(float4*)&wo_s[c * 68 + hq * 4] = v;
    }
    if (par == 0) {
        const float4 o0 = make_float4(acc[0] * inv, acc[1] * inv, acc[2] * inv, acc[3] * inv);
        const float4 o1 = make_float4(acc[4] * inv, acc[5] * inv, acc[6] * inv, acc[7] * inv);
        *(float4*)&y_s[px * 68 + oct * 8]     = o0;
        *(float4*)&y_s[px * 68 + oct * 8 + 4] = o1;
    }
    __syncthreads();

    // ---- out-projection + residual: thread = (channel 0..63, px 0..3) ----
    {
        const int px2 = tid & 3;
        const int cl  = tid >> 2;          // 0..63
        const int rr2 = px2 >> 1, cc2 = px2 & 1;
        const int gpix2 = (X0 + rr2) * WW + Y0 + cc2;
        float o0 = 0.f, o1 = 0.f;
#pragma unroll
        for (int h0 = 0; h0 < 16; ++h0) {
            const float4 yv = *(const float4*)&y_s[px2 * 68 + h0 * 4];
            const float4 w0 = *(const float4*)&wo_s[cl * 68 + h0 * 4];
            const float4 w1 = *(const float4*)&wo_s[(cl + 64) * 68 + h0 * 4];
            o0 = fmaf(w0.x, yv.x, o0); o0 = fmaf(w0.y, yv.y, o0);
            o0 = fmaf(w0.z, yv.z, o0); o0 = fmaf(w0.w, yv.w, o0);
            o1 = fmaf(w1.x, yv.x, o1); o1 = fmaf(w1.y, yv.y, o1);
            o1 = fmaf(w1.z, yv.z, o1); o1 = fmaf(w1.w, yv.w, o1);
        }
        const size_t c0 = (size_t)(b * CCH + cl);
        const size_t c1 = (size_t)(b * CCH + cl + 64);
        out[c0 * HWPIX + gpix2] = x[c0 * TT * HWPIX + gpix2] + o0;
        out[c1 * HWPIX + gpix2] = x[c1 * TT * HWPIX + gpix2] + o1;
    }
}

// ---------------------------------------------------------------------------
extern "C" void kernel_launch(void* const* d_in, const int* in_sizes, int n_in,
                              void* d_out, int out_size, void* d_ws, size_t ws_size,
                              hipStream_t stream)
{
    const float* x       = (const float*)d_in[0];
    const float* w_theta = (const float*)d_in[1];
    const float* w_phi   = (const float*)d_in[2];
    const float* w_g     = (const float*)d_in[3];
    const float* w_out   = (const float*)d_in[4];
    float* out = (float*)d_out;

    bf16_t* q_b   = (bf16_t*)d_ws;                        // 294912 elems
    bf16_t* phi_b = q_b + (size_t)BATCH * HWPIX * NHEAD;  // 2x 1179648 elems
    bf16_t* g_b   = phi_b + (size_t)GOFF;

    dim3 g1(HWPIX / 64, BATCH * TT);            // (36, 10)
    proj_kernel<<<g1, 256, 0, stream>>>(x, w_theta, w_phi, w_g, q_b, phi_b, g_b);

    attn_fused_kernel<<<1152, 256, 0, stream>>>(x, q_b, phi_b, w_out, out);
}

// Round 13
// 87.314 us; speedup vs baseline: 1.0408x; 1.0408x over previous
//
#include <hip/hip_runtime.h>
#include <hip/hip_bf16.h>
#include <math.h>

// B=2, C=128, T=5 (Tc=4 ctx), H=W=48, heads=64, PATCH=7 (pad 3), K=196.
#define BATCH 2
#define CCH 128
#define TT 5
#define TC 4
#define HH 48
#define WW 48
#define HWPIX 2304
#define NHEAD 64
#define PAD 3
#define XSTRIDE (TT*HWPIX)      // per-channel stride in x
#define PLANE (HWPIX*NHEAD)     // elements per UNPADDED (b,t) phi/g plane
#define GOFF (BATCH*TC*PLANE)   // g planes offset from phi planes (elements)

// fused-attn tile geometry: 4 wide x 2 tall pixel tile
#define TW 4
#define TH 2
#define WROWS 8                 // TH + 6
#define WCOLS 10                // TW + 6
#define NRC 80                  // WROWS*WCOLS
#define WELEM (NRC*NHEAD)       // 5120 bf16 per window buffer

#define WPITCH 136              // proj LDS pitch (bf16): 272B rows -> 2-way bank alias (free)

typedef unsigned short bf16_t;

static __device__ __forceinline__ bf16_t f2bf(float f) {
    unsigned u = __float_as_uint(f);
    u += 0x7FFFu + ((u >> 16) & 1u);          // round-to-nearest-even
    return (bf16_t)(u >> 16);
}
static __device__ __forceinline__ float bf_lo(unsigned u) {
    return __uint_as_float(u << 16);
}
static __device__ __forceinline__ float bf_hi(unsigned u) {
    return __uint_as_float(u & 0xFFFF0000u);
}
static __device__ __forceinline__ int iclamp(int v, int lo, int hi) {
    return v < lo ? lo : (v > hi ? hi : v);
}

// v_dot2_f32_bf16 path (hedged: falls back to unpack+fma if unavailable)
#if defined(__has_builtin)
#if __has_builtin(__builtin_amdgcn_fdot2_f32_bf16) && __has_builtin(__builtin_amdgcn_perm)
#define HAVE_DOT2 1
#endif
#endif

#ifdef HAVE_DOT2
typedef __bf16 bf16x2_t __attribute__((ext_vector_type(2)));
static __device__ __forceinline__ float dot2bf(unsigned g2, unsigned a2, float c) {
    return __builtin_amdgcn_fdot2_f32_bf16(
        __builtin_bit_cast(bf16x2_t, g2), __builtin_bit_cast(bf16x2_t, a2), c, false);
}
static __device__ __forceinline__ unsigned perm_lo(unsigned a, unsigned b) {
    return __builtin_amdgcn_perm(a, b, 0x05040100u);
}
static __device__ __forceinline__ unsigned perm_hi(unsigned a, unsigned b) {
    return __builtin_amdgcn_perm(a, b, 0x07060302u);
}
#else
static __device__ __forceinline__ float dot2bf(unsigned g2, unsigned a2, float c) {
    return c + bf_lo(g2) * bf_lo(a2) + bf_hi(g2) * bf_hi(a2);
}
#endif

typedef __attribute__((ext_vector_type(8))) short bf16x8;
typedef __attribute__((ext_vector_type(4))) float f32x4;

// ---------------------------------------------------------------------------
// K1: projections — MFMA, 64-px blocks (R9 optimum, unchanged).
// ---------------------------------------------------------------------------
__global__ __launch_bounds__(256) void proj_kernel(
    const float* __restrict__ x,
    const float* __restrict__ w_theta,
    const float* __restrict__ w_phi,
    const float* __restrict__ w_g,
    bf16_t* __restrict__ q_b,
    bf16_t* __restrict__ phi_b,
    bf16_t* __restrict__ g_b)
{
    __shared__ bf16_t xs[64 * WPITCH];      // 17.4 KB [px][c]
    __shared__ bf16_t wla[64 * WPITCH];     // 17.4 KB [h][c]  theta/phi
    __shared__ bf16_t wlb[64 * WPITCH];     // 17.4 KB [h][c]  g

    const int bt   = blockIdx.y;        // 0..9
    const int b    = bt / TT;
    const int t    = bt % TT;
    const int tid  = threadIdx.x;
    const int lane = tid & 63;
    const int wv   = tid >> 6;          // 0..3 = 16-px tile
    const int p0   = blockIdx.x * 64;

    // ---- stage weights from fp32, packing to bf16 [h][c] rows ----
    {
        const float* srcA = (t == 0) ? w_theta : w_phi;
#pragma unroll
        for (int i = 0; i < 4; ++i) {
            const int idx = i * 256 + tid;   // 0..1023
            const int h   = idx >> 4;        // 0..63
            const int ck  = idx & 15;        // chunk 0..15
            const float* s = srcA + h * CCH + ck * 8;
            const float4 v0 = *(const float4*)(s);
            const float4 v1 = *(const float4*)(s + 4);
            uint4 o;
            o.x = (unsigned)f2bf(v0.x) | ((unsigned)f2bf(v0.y) << 16);
            o.y = (unsigned)f2bf(v0.z) | ((unsigned)f2bf(v0.w) << 16);
            o.z = (unsigned)f2bf(v1.x) | ((unsigned)f2bf(v1.y) << 16);
            o.w = (unsigned)f2bf(v1.z) | ((unsigned)f2bf(v1.w) << 16);
            *(uint4*)&wla[h * WPITCH + ck * 8] = o;
        }
        if (t != 0) {
#pragma unroll
            for (int i = 0; i < 4; ++i) {
                const int idx = i * 256 + tid;
                const int h   = idx >> 4;
                const int ck  = idx & 15;
                const float* s = w_g + h * CCH + ck * 8;
                const float4 v0 = *(const float4*)(s);
                const float4 v1 = *(const float4*)(s + 4);
                uint4 o;
                o.x = (unsigned)f2bf(v0.x) | ((unsigned)f2bf(v0.y) << 16);
                o.y = (unsigned)f2bf(v0.z) | ((unsigned)f2bf(v0.w) << 16);
                o.z = (unsigned)f2bf(v1.x) | ((unsigned)f2bf(v1.y) << 16);
                o.w = (unsigned)f2bf(v1.z) | ((unsigned)f2bf(v1.w) << 16);
                *(uint4*)&wlb[h * WPITCH + ck * 8] = o;
            }
        }
    }

    // ---- stage x tile as bf16 [px][c] (lanes over 64 px: 256B coalesced) ----
    {
        const float* xsrc = x + ((size_t)(b * CCH) * TT + t) * HWPIX + p0;
#pragma unroll
        for (int i = 0; i < 16; ++i) {
            const int idx = i * 256 + tid;  // 0..4095
            const int cp  = idx >> 6;       // c-pair 0..63
            const int px  = idx & 63;
            const float a0 = xsrc[(size_t)(2 * cp)     * XSTRIDE + px];
            const float a1 = xsrc[(size_t)(2 * cp + 1) * XSTRIDE + px];
            *(unsigned*)&xs[px * WPITCH + 2 * cp] =
                (unsigned)f2bf(a0) | ((unsigned)f2bf(a1) << 16);
        }
    }
    __syncthreads();

    // ---- MFMA K-loop ----
    const int arow = wv * 16 + (lane & 15);
    const int koff = (lane >> 4) * 8;

    bf16x8 afr[4];
#pragma unroll
    for (int kk = 0; kk < 4; ++kk)
        afr[kk] = *(const bf16x8*)&xs[arow * WPITCH + koff + 32 * kk];

    const int hrow16 = lane & 15;              // B-frag row within h-tile
    const int prow_  = (lane >> 4) * 4;        // D row base (px within tile)
    const int hcol   = lane & 15;              // D col (h within 16-tile)

    if (t == 0) {
#pragma unroll
        for (int ht = 0; ht < 4; ++ht) {
            f32x4 acc = {0.f, 0.f, 0.f, 0.f};
#pragma unroll
            for (int kk = 0; kk < 4; ++kk) {
                const bf16x8 bfr = *(const bf16x8*)&wla[(ht * 16 + hrow16) * WPITCH + koff + 32 * kk];
                acc = __builtin_amdgcn_mfma_f32_16x16x32_bf16(afr[kk], bfr, acc, 0, 0, 0);
            }
            const int h = ht * 16 + hcol;
#pragma unroll
            for (int r = 0; r < 4; ++r) {
                const int px = p0 + wv * 16 + prow_ + r;
                q_b[((size_t)b * HWPIX + px) * NHEAD + h] = f2bf(acc[r]);
            }
        }
    } else {
        const size_t base = (size_t)(b * TC + (t - 1)) * PLANE;
#pragma unroll
        for (int pr = 0; pr < 2; ++pr) {
            const bf16_t* wl = pr ? wlb : wla;
            bf16_t* dst = pr ? g_b : phi_b;
#pragma unroll
            for (int ht = 0; ht < 4; ++ht) {
                f32x4 acc = {0.f, 0.f, 0.f, 0.f};
#pragma unroll
                for (int kk = 0; kk < 4; ++kk) {
                    const bf16x8 bfr = *(const bf16x8*)&wl[(ht * 16 + hrow16) * WPITCH + koff + 32 * kk];
                    acc = __builtin_amdgcn_mfma_f32_16x16x32_bf16(afr[kk], bfr, acc, 0, 0, 0);
                }
                const int h = ht * 16 + hcol;
#pragma unroll
                for (int r = 0; r < 4; ++r) {
                    const int px = p0 + wv * 16 + prow_ + r;
                    dst[base + (size_t)px * NHEAD + h] = f2bf(acc[r]);
                }
            }
        }
    }
}

// ---------------------------------------------------------------------------
// K2: FUSED attention + combine + out-proj + residual (R10 optimum).
// Pair-key logits (ls2 packed direct from registers, no ls[] round-trips),
// split 16-deep dot2 chains, deferred l-sum, setprio around compute,
// XCD-chunked swizzle, clamp-at-staging replicate padding.
// ---------------------------------------------------------------------------
__global__ __launch_bounds__(256) void attn_fused_kernel(
    const float* __restrict__ x,
    const bf16_t* __restrict__ q_b,
    const bf16_t* __restrict__ pg,      // phi planes; g planes at pg + GOFF
    const float* __restrict__ w_out,
    float* __restrict__ out)
{
    __shared__ __align__(16) char smem[4 * WELEM * 2];  // 40960 B win / alias
    __shared__ unsigned ls2[8][26];
    __shared__ unsigned prow[26];

    const int tid = threadIdx.x;
    const int px  = tid >> 5;           // 0..7 pixel of tile
    const int sub = tid & 31;

    // ---- XCD-chunked swizzle: bid%8 = XCD, contiguous 72-tile chunk each ----
    const int bid = blockIdx.x;
    const int lin = (bid & 7) * 72 + (bid >> 3);   // bijective (576 = 8*72)
    const int b   = lin / 288;
    const int rem = lin - b * 288;
    const int ty  = rem / 12;
    const int tx  = rem - ty * 12;
    const int Y0  = tx * TW;
    const int X0  = ty * TH;

    const int rr  = px >> 2;
    const int cc  = px & 3;
    const int gpix  = (X0 + rr) * WW + Y0 + cc;
    const int pxoff = rr * WCOLS + cc;
    const int oct = sub >> 2;
    const int par = sub & 3;

    // ---- q fragments (64 h = 8 uint4), broadcast across 32 sub-lanes ----
    uint4 qu[8];
    {
        const uint4* qs = (const uint4*)(q_b + ((size_t)b * HWPIX + gpix) * NHEAD);
#pragma unroll
        for (int ch = 0; ch < 8; ++ch) qu[ch] = qs[ch];
    }

    if (tid < 25) {
        const int k0 = 2 * tid;
        const int k1 = (k0 + 1 < 49) ? k0 + 1 : 48;
        const unsigned r0 = (unsigned)((k0 / 7) * WCOLS + (k0 % 7));
        const unsigned r1 = (unsigned)((k1 / 7) * WCOLS + (k1 % 7));
        prow[tid] = r0 | (r1 << 16);
    }

    // ---- per-thread staging offsets: 1280 uint4 per stage = 5/thread.
    //      Replicate padding realized here: clamp window coords to [0,47]. ----
    int srcoff[5], lddst[5];
#pragma unroll
    for (int ii = 0; ii < 5; ++ii) {
        const int idx  = ii * 256 + tid;          // 0..1279
        const int isg  = (idx >= 640) ? 1 : 0;    // 0: phi, 1: g
        const int idx2 = idx - (isg ? 640 : 0);
        const int row  = idx2 >> 3;               // 0..79
        const int ch   = idx2 & 7;
        const int i    = row / WCOLS;
        const int c    = row - i * WCOLS;
        const int xr   = iclamp(X0 + i - PAD, 0, HH - 1);
        const int yc   = iclamp(Y0 + c - PAD, 0, WW - 1);
        srcoff[ii] = isg * GOFF + (xr * WW + yc) * NHEAD + ch * 8;
        lddst[ii]  = isg * (2 * WELEM) + row * NHEAD + (((ch + row) & 7) << 3);
    }

    bf16_t* winb = (bf16_t*)smem;   // [phi0 | phi1 | g0 | g1], 5120 elems each

    // ---- prologue: stage t=0 into parity 0 ----
    {
        const bf16_t* sp = pg + (size_t)(b * TC) * PLANE;
#pragma unroll
        for (int ii = 0; ii < 5; ++ii) {
            const uint4 v = *(const uint4*)(sp + srcoff[ii]);
            *(uint4*)(winb + lddst[ii]) = v;
        }
    }
    __syncthreads();

    float m_run = -INFINITY, l_part = 0.f;
    float acc[8];
#pragma unroll
    for (int e = 0; e < 8; ++e) acc[e] = 0.f;

    for (int t = 0; t < TC; ++t) {
        const int p = t & 1;

        // ---- issue next-t loads early (hidden under logits+PV) ----
        uint4 stg[5];
        if (t < TC - 1) {
            const bf16_t* sp = pg + (size_t)(b * TC + t + 1) * PLANE;
#pragma unroll
            for (int ii = 0; ii < 5; ++ii)
                stg[ii] = *(const uint4*)(sp + srcoff[ii]);
        }

        __builtin_amdgcn_s_setprio(1);

        // ---- logits: PAIR keys k = 2*sub, 2*sub+1 (lanes 0..24) ----
        const bf16_t* pbase = winb + p * WELEM;
        float v0 = -INFINITY, v1 = -INFINITY;
        if (sub < 25) {
            {
                const int k = 2 * sub;
                const int i = k / 7, j = k - i * 7;
                const int row = i * WCOLS + j + pxoff;
                const bf16_t* base = pbase + row * NHEAD;
                float sa = 0.f, sb = 0.f;     // split chains: 16-deep each
#pragma unroll
                for (int ch = 0; ch < 4; ++ch) {
                    const uint4 u  = *(const uint4*)&base[((ch + row) & 7) << 3];
                    const uint4 u2 = *(const uint4*)&base[((ch + 4 + row) & 7) << 3];
                    sa = dot2bf(u.x,  qu[ch].x,     sa);
                    sa = dot2bf(u.y,  qu[ch].y,     sa);
                    sa = dot2bf(u.z,  qu[ch].z,     sa);
                    sa = dot2bf(u.w,  qu[ch].w,     sa);
                    sb = dot2bf(u2.x, qu[ch + 4].x, sb);
                    sb = dot2bf(u2.y, qu[ch + 4].y, sb);
                    sb = dot2bf(u2.z, qu[ch + 4].z, sb);
                    sb = dot2bf(u2.w, qu[ch + 4].w, sb);
                }
                v0 = (sa + sb) * 8.0f;    // * sqrt(64)
            }
            if (2 * sub + 1 < 49) {
                const int k = 2 * sub + 1;
                const int i = k / 7, j = k - i * 7;
                const int row = i * WCOLS + j + pxoff;
                const bf16_t* base = pbase + row * NHEAD;
                float sa = 0.f, sb = 0.f;
#pragma unroll
                for (int ch = 0; ch < 4; ++ch) {
                    const uint4 u  = *(const uint4*)&base[((ch + row) & 7) << 3];
                    const uint4 u2 = *(const uint4*)&base[((ch + 4 + row) & 7) << 3];
                    sa = dot2bf(u.x,  qu[ch].x,     sa);
                    sa = dot2bf(u.y,  qu[ch].y,     sa);
                    sa = dot2bf(u.z,  qu[ch].z,     sa);
                    sa = dot2bf(u.w,  qu[ch].w,     sa);
                    sb = dot2bf(u2.x, qu[ch + 4].x, sb);
                    sb = dot2bf(u2.y, qu[ch + 4].y, sb);
                    sb = dot2bf(u2.z, qu[ch + 4].z, sb);
                    sb = dot2bf(u2.w, qu[ch + 4].w, sb);
                }
                v1 = (sa + sb) * 8.0f;
            }
        }

        // ---- online softmax: max reduce; exp pairs pack DIRECT to ls2 ----
        float mt = fmaxf(v0, v1);
#pragma unroll
        for (int d = 1; d < 32; d <<= 1) mt = fmaxf(mt, __shfl_xor(mt, d));
        const float m_new = fmaxf(m_run, mt);
        const float sc = __expf(m_run - m_new);
        float e0 = 0.f, e1 = 0.f;
        if (sub < 25) {
            e0 = __expf(v0 - m_new);
            e1 = (2 * sub + 1 < 49) ? __expf(v1 - m_new) : 0.f;
            ls2[px][sub] = (unsigned)f2bf(e0) | ((unsigned)f2bf(e1) << 16);
        }
        l_part = l_part * sc + e0 + e1;
        m_run = m_new;

        // ---- PV accumulate with rescale ----
#pragma unroll
        for (int e = 0; e < 8; ++e) acc[e] *= sc;
        const bf16_t* gbase = winb + 2 * WELEM + p * WELEM;
#pragma unroll
        for (int mi = 0; mi < 7; ++mi) {
            const int pm = par + 4 * mi;
            if (pm < 25) {
                const unsigned pr = prow[pm];
                const int row0 = (int)(pr & 0xFFFFu) + pxoff;
                const int row1 = (int)(pr >> 16) + pxoff;
                const uint4 u0 = *(const uint4*)&gbase[row0 * NHEAD + (((oct + row0) & 7) << 3)];
                const uint4 u1 = *(const uint4*)&gbase[row1 * NHEAD + (((oct + row1) & 7) << 3)];
#ifdef HAVE_DOT2
                const unsigned a2 = ls2[px][pm];
                acc[0] = dot2bf(perm_lo(u1.x, u0.x), a2, acc[0]);
                acc[1] = dot2bf(perm_hi(u1.x, u0.x), a2, acc[1]);
                acc[2] = dot2bf(perm_lo(u1.y, u0.y), a2, acc[2]);
                acc[3] = dot2bf(perm_hi(u1.y, u0.y), a2, acc[3]);
                acc[4] = dot2bf(perm_lo(u1.z, u0.z), a2, acc[4]);
                acc[5] = dot2bf(perm_hi(u1.z, u0.z), a2, acc[5]);
                acc[6] = dot2bf(perm_lo(u1.w, u0.w), a2, acc[6]);
                acc[7] = dot2bf(perm_hi(u1.w, u0.w), a2, acc[7]);
#else
                const unsigned a2 = ls2[px][pm];
                const float a0 = bf_lo(a2), a1 = bf_hi(a2);
                acc[0] = fmaf(a1, bf_lo(u1.x), fmaf(a0, bf_lo(u0.x), acc[0]));
                acc[1] = fmaf(a1, bf_hi(u1.x), fmaf(a0, bf_hi(u0.x), acc[1]));
                acc[2] = fmaf(a1, bf_lo(u1.y), fmaf(a0, bf_lo(u0.y), acc[2]));
                acc[3] = fmaf(a1, bf_hi(u1.y), fmaf(a0, bf_hi(u0.y), acc[3]));
                acc[4] = fmaf(a1, bf_lo(u1.z), fmaf(a0, bf_lo(u0.z), acc[4]));
                acc[5] = fmaf(a1, bf_hi(u1.z), fmaf(a0, bf_hi(u0.z), acc[5]));
                acc[6] = fmaf(a1, bf_lo(u1.w), fmaf(a0, bf_lo(u0.w), acc[6]));
                acc[7] = fmaf(a1, bf_hi(u1.w), fmaf(a0, bf_hi(u0.w), acc[7]));
#endif
            }
        }

        __builtin_amdgcn_s_setprio(0);

        // ---- write-late: next-t windows into alternate buffers ----
        if (t < TC - 1) {
            bf16_t* dp = winb + (p ^ 1) * WELEM;   // g offset baked into lddst
#pragma unroll
            for (int ii = 0; ii < 5; ++ii)
                *(uint4*)(dp + lddst[ii]) = stg[ii];
        }
        __syncthreads();
    }

    // ---- deferred l reduce (once), then par reduce of acc ----
#pragma unroll
    for (int d = 1; d < 32; d <<= 1) l_part += __shfl_xor(l_part, d);
#pragma unroll
    for (int e = 0; e < 8; ++e) {
        acc[e] += __shfl_xor(acc[e], 1);
        acc[e] += __shfl_xor(acc[e], 2);
    }
    const float inv = 1.0f / l_part;

    // ---- epilogue: alias win LDS as w_out tile + y tile ----
    float* wo_s = (float*)smem;                        // [128][68] = 34816 B
    float* y_s  = (float*)(smem + 128 * 68 * 4);       // [8][68]   =  2176 B

#pragma unroll
    for (int ii = 0; ii < 8; ++ii) {
        const int idx = ii * 256 + tid;    // 0..2047
        const int c   = idx >> 4;
        const int hq  = idx & 15;
        const float4 v = *(const float4*)(w_out + (size_t)c * NHEAD + hq * 4);
        *(float4*)&wo_s[c * 68 + hq * 4] = v;
    }
    if (par == 0) {
        const float4 o0 = make_float4(acc[0] * inv, acc[1] * inv, acc[2] * inv, acc[3] * inv);
        const float4 o1 = make_float4(acc[4] * inv, acc[5] * inv, acc[6] * inv, acc[7] * inv);
        *(float4*)&y_s[px * 68 + oct * 8]     = o0;
        *(float4*)&y_s[px * 68 + oct * 8 + 4] = o1;
    }
    __syncthreads();

    // ---- out-projection + residual ----
    {
        const int px2 = tid & 7;
        const int cl  = tid >> 3;          // 0..31
        const int rr2 = px2 >> 2, cc2 = px2 & 3;
        const int gpix2 = (X0 + rr2) * WW + Y0 + cc2;
        float o[4] = {0.f, 0.f, 0.f, 0.f};
#pragma unroll
        for (int h0 = 0; h0 < 16; ++h0) {
            const float4 yv = *(const float4*)&y_s[px2 * 68 + h0 * 4];
#pragma unroll
            for (int it = 0; it < 4; ++it) {
                const float4 wv = *(const float4*)&wo_s[(cl + 32 * it) * 68 + h0 * 4];
                o[it] = fmaf(wv.x, yv.x, o[it]);
                o[it] = fmaf(wv.y, yv.y, o[it]);
                o[it] = fmaf(wv.z, yv.z, o[it]);
                o[it] = fmaf(wv.w, yv.w, o[it]);
            }
        }
#pragma unroll
        for (int it = 0; it < 4; ++it) {
            const size_t ccg = (size_t)(b * CCH + cl + 32 * it);
            const float xi = x[ccg * TT * HWPIX + gpix2];
            out[ccg * HWPIX + gpix2] = xi + o[it];
        }
    }
}

// ---------------------------------------------------------------------------
extern "C" void kernel_launch(void* const* d_in, const int* in_sizes, int n_in,
                              void* d_out, int out_size, void* d_ws, size_t ws_size,
                              hipStream_t stream)
{
    const float* x       = (const float*)d_in[0];
    const float* w_theta = (const float*)d_in[1];
    const float* w_phi   = (const float*)d_in[2];
    const float* w_g     = (const float*)d_in[3];
    const float* w_out   = (const float*)d_in[4];
    float* out = (float*)d_out;

    bf16_t* q_b   = (bf16_t*)d_ws;                        // 294912 elems
    bf16_t* phi_b = q_b + (size_t)BATCH * HWPIX * NHEAD;  // 2x 1179648 elems
    bf16_t* g_b   = phi_b + (size_t)GOFF;

    dim3 g1(HWPIX / 64, BATCH * TT);            // (36, 10)
    proj_kernel<<<g1, 256, 0, stream>>>(x, w_theta, w_phi, w_g, q_b, phi_b, g_b);

    attn_fused_kernel<<<576, 256, 0, stream>>>(x, q_b, phi_b, w_out, out);
}